// Round 1
// 4384.659 us; speedup vs baseline: 1.8060x; 1.8060x over previous
//
#include <hip/hip_runtime.h>
#include <stdint.h>
#include <stddef.h>

typedef __attribute__((ext_vector_type(8))) short short8;
typedef __attribute__((ext_vector_type(4))) float floatx4;

#define Bn 8
#define Cn 32
#define Hn 512
#define Wn 512
#define NCH 32          // chunks per batch
#define RR 16           // own rows per chunk
#define GR 8            // ghost depth == columns per sync epoch
#define REG (RR + 2*GR) // 32 region rows per WG
#define PROWS (REG + 2) // +2 stencil pad rows -> 34
#define NWG (Bn*NCH)    // 256
#define PST 40          // P row stride (bf16 elems); 80B = multiple of 16B

__device__ __forceinline__ unsigned short f2bf(float f) {
  union { float f; unsigned int i; } v; v.f = f;
  unsigned int x = v.i;
  unsigned int r = x + 0x7fffu + ((x >> 16) & 1u);  // RNE
  return (unsigned short)(r >> 16);
}
__device__ __forceinline__ float sigmoidf_(float x) {
  return 1.0f / (1.0f + __expf(-x));
}
__device__ __forceinline__ float tanhf_(float x) {
  return 1.0f - 2.0f / (__expf(2.0f * x) + 1.0f);
}

// Ghost-zone (trapezoidal) scan: one wave per WG, one WG per (batch, 16-row chunk).
// Region = 16 own rows + 8 ghost rows each side. Halo exchange through agent-scope
// memory happens only every GR=8 columns; between syncs ghost rows evolve with
// locally-stale data, invalidating 1 row/side/column -> own rows stay BIT-EXACT
// for up to 8 steps (exactly the epoch length). This amortizes the cross-XCD
// release/acquire round trip (the measured ~14 us/column serial chain) 8x.
__global__ __launch_bounds__(64, 1) void sdn_scan(
    const float* __restrict__ states,  // (B,C,H,W) f32
    const float* __restrict__ wih,     // (96,96) f32
    const float* __restrict__ bih,     // (96)
    const float* __restrict__ whh,     // (96,32)
    const float* __restrict__ bhh,     // (96)
    float* __restrict__ out,           // (B,C,H,W) f32
    unsigned int* __restrict__ bnd,    // [NWG][2 parity][2 dir][128] uints = 512 KB
    int* __restrict__ flags)           // [NWG][2 parity] epoch tags
{
  const int lane = threadIdx.x;
  const int wg = blockIdx.x;
  const int b = wg & 7;      // batch
  const int j = wg >> 3;     // chunk within batch (neighbors wg+-8 share an XCD)
  const int h0 = j * RR;     // first OWN row
  const int lm = lane & 15;
  const int lg = lane >> 4;

  __shared__ __align__(16) unsigned short P[PROWS * PST];  // prev column (bf16)

  // ---- persistent weight fragments (B-operand layout: B[k][n], n=lm, k=lg*8+t) ----
  short8 wf[6][3];
  short8 hf[6];
  float bi[6], bh[6];
  for (int ot = 0; ot < 6; ++ot) {
    for (int ks = 0; ks < 3; ++ks) {
      short8 v;
#pragma unroll
      for (int t = 0; t < 8; ++t)
        v[t] = (short)f2bf(wih[(size_t)(16 * ot + lm) * 96 + 32 * ks + lg * 8 + t]);
      wf[ot][ks] = v;
    }
    short8 v;
#pragma unroll
    for (int t = 0; t < 8; ++t)
      v[t] = (short)f2bf(whh[(size_t)(16 * ot + lm) * 32 + lg * 8 + t]);
    hf[ot] = v;
    bi[ot] = bih[16 * ot + lm];
    bh[ot] = bhh[16 * ot + lm];
  }

  // ---- init P with column 0 over the whole ghost-extended region (+pad rows) ----
  // P row pr <-> global row h0 - GR - 1 + pr. All rows globally valid at col 0.
  for (int t = lane; t < PROWS * 32; t += 64) {
    int pr = t >> 5, c = t & 31;
    int h = h0 - GR - 1 + pr;
    unsigned short v = 0;
    if ((unsigned)h < (unsigned)Hn)
      v = f2bf(states[(((size_t)b * Cn + c) * Hn + h) * Wn + 0]);
    P[pr * PST + c] = v;
  }
  // ---- column 0 of output = input column 0 (own rows, exact f32 copy) ----
  for (int t = lane; t < RR * 32; t += 64) {
    int r = t >> 5, c = t & 31;
    size_t idx = (((size_t)b * Cn + c) * Hn + (h0 + r)) * Wn + 0;
    out[idx] = states[idx];
  }

  // ---- preload cur column 1 for both 16-row tiles (zero outside H range) ----
  short8 curA[2];       // A[m=lm][k] = cur[region row 16*tl+lm][c=k]
  float curC[2][2][4];  // (region row 16*tl+lg*4+i, c=16*tt+lm), exact f32
#pragma unroll
  for (int tl = 0; tl < 2; ++tl) {
    int hA = h0 - GR + 16 * tl + lm;
#pragma unroll
    for (int t = 0; t < 8; ++t) {
      int c = lg * 8 + t;
      curA[tl][t] = ((unsigned)hA < (unsigned)Hn)
          ? (short)f2bf(states[(((size_t)b * Cn + c) * Hn + hA) * Wn + 1]) : (short)0;
    }
#pragma unroll
    for (int tt = 0; tt < 2; ++tt)
#pragma unroll
      for (int i = 0; i < 4; ++i) {
        int h = h0 - GR + 16 * tl + lg * 4 + i;
        curC[tl][tt][i] = ((unsigned)h < (unsigned)Hn)
            ? states[(((size_t)b * Cn + (16 * tt + lm)) * Hn + h) * Wn + 1] : 0.f;
      }
  }

  for (int w = 1; w < Wn; ++w) {
    // ---- A fragments for BOTH tiles before any P write (stencils overlap at row 16) ----
    short8 af[2][3];
#pragma unroll
    for (int tl = 0; tl < 2; ++tl)
#pragma unroll
      for (int ks = 0; ks < 3; ++ks)
        af[tl][ks] = *(const short8*)&P[(16 * tl + lm + ks) * PST + lg * 8];

    // ---- issue prefetch of column w+1 early; latency hides under MFMA+gates ----
    short8 nA[2];
    float nC[2][2][4];
    if (w + 1 < Wn) {
#pragma unroll
      for (int tl = 0; tl < 2; ++tl) {
        int hA = h0 - GR + 16 * tl + lm;
#pragma unroll
        for (int t = 0; t < 8; ++t) {
          int c = lg * 8 + t;
          nA[tl][t] = ((unsigned)hA < (unsigned)Hn)
              ? (short)f2bf(states[(((size_t)b * Cn + c) * Hn + hA) * Wn + (w + 1)]) : (short)0;
        }
#pragma unroll
        for (int tt = 0; tt < 2; ++tt)
#pragma unroll
          for (int i = 0; i < 4; ++i) {
            int h = h0 - GR + 16 * tl + lg * 4 + i;
            nC[tl][tt][i] = ((unsigned)h < (unsigned)Hn)
                ? states[(((size_t)b * Cn + (16 * tt + lm)) * Hn + h) * Wn + (w + 1)] : 0.f;
          }
      }
    }

    // ---- per tile: MFMA -> gates -> out store (own rows only) + P update ----
#pragma unroll
    for (int tl = 0; tl < 2; ++tl) {
      floatx4 I[6], Hh[6];
#pragma unroll
      for (int ot = 0; ot < 6; ++ot) {
        I[ot] = (floatx4){bi[ot], bi[ot], bi[ot], bi[ot]};
        Hh[ot] = (floatx4){bh[ot], bh[ot], bh[ot], bh[ot]};
#pragma unroll
        for (int ks = 0; ks < 3; ++ks)
          I[ot] = __builtin_amdgcn_mfma_f32_16x16x32_bf16(af[tl][ks], wf[ot][ks], I[ot], 0, 0, 0);
        Hh[ot] = __builtin_amdgcn_mfma_f32_16x16x32_bf16(curA[tl], hf[ot], Hh[ot], 0, 0, 0);
      }
#pragma unroll
      for (int tt = 0; tt < 2; ++tt) {
#pragma unroll
        for (int i = 0; i < 4; ++i) {
          float rv = sigmoidf_(I[tt][i] + Hh[tt][i]);
          float zv = sigmoidf_(I[2 + tt][i] + Hh[2 + tt][i]);
          float nv = tanhf_(I[4 + tt][i] + rv * Hh[4 + tt][i]);
          float ov = curC[tl][tt][i] + zv * (nv - curC[tl][tt][i]);
          int c = 16 * tt + lm;
          int rr = 16 * tl + lg * 4 + i;  // region row
          P[(1 + rr) * PST + c] = f2bf(ov);
          bool own = (tl == 0) ? (lg >= 2) : (lg < 2);  // region rows [8,24)
          if (own)
            out[(((size_t)b * Cn + c) * Hn + (h0 - GR + rr)) * Wn + w] = ov;
        }
      }
      // H-boundary chunks: force the pad-adjacent ghost row to zero every column
      // (emulates the reference's 1-row zero pad; blocks garbage propagation).
      if (tl == 0 && j == 0 && lane < 32) P[8 * PST + lane] = 0;          // global row -1
      if (tl == 1 && j == NCH - 1 && lane < 32) P[25 * PST + lane] = 0;   // global row 512
    }

    // ---- halo exchange every GR columns (w = 8,16,...,504) ----
    if ((w & (GR - 1)) == 0) {
      const int par = (w >> 3) & 1;
      const int base = (wg * 2 + par) * 256;
      // publish own top 8 rows (P rows 9..16 -> dir0) and bottom 8 (P 17..24 -> dir1)
#pragma unroll
      for (int u0 = 0; u0 < 2; ++u0) {
        int u = lane + 64 * u0;
        int row = u >> 4, cp = (u & 15) * 2;
        unsigned int v0 = (unsigned int)P[(9 + row) * PST + cp] |
                          ((unsigned int)P[(9 + row) * PST + cp + 1] << 16);
        unsigned int v1 = (unsigned int)P[(17 + row) * PST + cp] |
                          ((unsigned int)P[(17 + row) * PST + cp + 1] << 16);
        __hip_atomic_store(&bnd[base + u], v0, __ATOMIC_RELAXED, __HIP_MEMORY_SCOPE_AGENT);
        __hip_atomic_store(&bnd[base + 128 + u], v1, __ATOMIC_RELAXED, __HIP_MEMORY_SCOPE_AGENT);
      }
      __hip_atomic_store(&flags[wg * 2 + par], w, __ATOMIC_RELEASE, __HIP_MEMORY_SCOPE_AGENT);

      if (j > 0) {  // up neighbor's bottom own rows -> my ghost P rows 1..8
        const int nb = wg - 8;
        int spins = 0;
        while (__hip_atomic_load(&flags[nb * 2 + par], __ATOMIC_ACQUIRE,
                                 __HIP_MEMORY_SCOPE_AGENT) != w) {
          __builtin_amdgcn_s_sleep(2);
          if (++spins > (1 << 20)) break;  // fail loud (wrong result), not hung
        }
#pragma unroll
        for (int u0 = 0; u0 < 2; ++u0) {
          int u = lane + 64 * u0;
          int row = u >> 4, cp = (u & 15) * 2;
          unsigned int v = __hip_atomic_load(&bnd[(nb * 2 + par) * 256 + 128 + u],
                                             __ATOMIC_RELAXED, __HIP_MEMORY_SCOPE_AGENT);
          P[(1 + row) * PST + cp] = (unsigned short)(v & 0xffffu);
          P[(1 + row) * PST + cp + 1] = (unsigned short)(v >> 16);
        }
      }
      if (j < NCH - 1) {  // down neighbor's top own rows -> my ghost P rows 25..32
        const int nb = wg + 8;
        int spins = 0;
        while (__hip_atomic_load(&flags[nb * 2 + par], __ATOMIC_ACQUIRE,
                                 __HIP_MEMORY_SCOPE_AGENT) != w) {
          __builtin_amdgcn_s_sleep(2);
          if (++spins > (1 << 20)) break;
        }
#pragma unroll
        for (int u0 = 0; u0 < 2; ++u0) {
          int u = lane + 64 * u0;
          int row = u >> 4, cp = (u & 15) * 2;
          unsigned int v = __hip_atomic_load(&bnd[(nb * 2 + par) * 256 + u],
                                             __ATOMIC_RELAXED, __HIP_MEMORY_SCOPE_AGENT);
          P[(25 + row) * PST + cp] = (unsigned short)(v & 0xffffu);
          P[(25 + row) * PST + cp + 1] = (unsigned short)(v >> 16);
        }
      }
    }

    // ---- roll prefetched inputs (after sync so the load-wait lands post-spin) ----
    if (w + 1 < Wn) {
#pragma unroll
      for (int tl = 0; tl < 2; ++tl) {
        curA[tl] = nA[tl];
#pragma unroll
        for (int tt = 0; tt < 2; ++tt)
#pragma unroll
          for (int i = 0; i < 4; ++i)
            curC[tl][tt][i] = nC[tl][tt][i];
      }
    }
  }
}

extern "C" void kernel_launch(void* const* d_in, const int* in_sizes, int n_in,
                              void* d_out, int out_size, void* d_ws, size_t ws_size,
                              hipStream_t stream) {
  const float* states = (const float*)d_in[0];
  const float* wih = (const float*)d_in[1];
  const float* bih = (const float*)d_in[2];
  const float* whh = (const float*)d_in[3];
  const float* bhh = (const float*)d_in[4];
  float* outp = (float*)d_out;

  unsigned int* bnd = (unsigned int*)d_ws;  // NWG*2*2*128 uints = 512 KB
  int* flags = (int*)((char*)d_ws + (size_t)NWG * 2 * 256 * sizeof(unsigned int));

  // zero the epoch-tag flags each call (ws is re-poisoned by the harness)
  hipMemsetAsync(flags, 0, (size_t)NWG * 2 * sizeof(int), stream);

  sdn_scan<<<dim3(NWG), dim3(64), 0, stream>>>(states, wih, bih, whh, bhh, outp, bnd, flags);
}

// Round 2
// 2186.646 us; speedup vs baseline: 3.6215x; 2.0052x over previous
//
#include <hip/hip_runtime.h>
#include <stdint.h>
#include <stddef.h>

typedef __attribute__((ext_vector_type(8))) short short8;
typedef __attribute__((ext_vector_type(4))) float floatx4;

#define Bn 8
#define Cn 32
#define Hn 512
#define Wn 512
#define NCH 32          // chunks per batch
#define RR 16           // own rows per chunk
#define GR 8            // ghost depth == columns per sync epoch
#define WT 8            // columns per staged tile (== GR)
#define NT (Wn/WT)      // 64 tiles
#define NWG (Bn*NCH)    // 256
#define PST 40          // P row stride (bf16 elems); 80B = 16B multiple
#define OST 9           // OUT w-stride (f32), odd pad -> conflict-light writes

__device__ __forceinline__ unsigned short f2bf(float f) {
  union { float f; unsigned int i; } v; v.f = f;
  unsigned int x = v.i;
  unsigned int r = x + 0x7fffu + ((x >> 16) & 1u);  // RNE
  return (unsigned short)(r >> 16);
}
__device__ __forceinline__ float sigmoidf_(float x) {
  return 1.0f / (1.0f + __expf(-x));
}
__device__ __forceinline__ float tanhf_(float x) {
  return 1.0f - 2.0f / (__expf(2.0f * x) + 1.0f);
}

// Ghost-zone scan + tiled I/O staging.
// One wave per WG; region = 16 own rows + 8 ghost rows each side; halo sync
// every 8 columns (amortized cross-XCD release/acquire). NEW this version:
// all global traffic is batched per 8-column tile through LDS --
//   IN  [8w][32row][32c] f32 : coalesced float4 loads, transpose via regs
//   OUT [16row][32c][9w] f32 : coalesced float4 stores at tile end
// so the serial column loop issues ZERO global memory operations.
__global__ __launch_bounds__(64, 1) void sdn_scan(
    const float* __restrict__ states,  // (B,C,H,W) f32
    const float* __restrict__ wih,     // (96,96) f32
    const float* __restrict__ bih,     // (96)
    const float* __restrict__ whh,     // (96,32)
    const float* __restrict__ bhh,     // (96)
    float* __restrict__ out,           // (B,C,H,W) f32
    unsigned int* __restrict__ bnd,    // [NWG][2 parity][2 dir][128]
    int* __restrict__ flags)           // [NWG][2 parity] epoch tags
{
  const int lane = threadIdx.x;
  const int wg = blockIdx.x;
  const int b = wg & 7;      // batch
  const int j = wg >> 3;     // chunk within batch (neighbors wg+-8 on one XCD)
  const int h0 = j * RR;     // first OWN row
  const int lm = lane & 15;
  const int lg = lane >> 4;
  const int cS = lane >> 1;  // staging: channel
  const int qS = lane & 1;   // staging: w-quad (0 -> w0..w0+3, 1 -> w0+4..w0+7)

  __shared__ __align__(16) unsigned short P[34 * PST];   // prev column (bf16)
  __shared__ __align__(16) float INS[WT * 32 * 32];      // input tile, 32 KB
  __shared__ __align__(16) float OUTS[RR * 32 * OST];    // output tile, 18 KB

  // ---- persistent weight fragments (B-operand layout: B[k][n], n=lm, k=lg*8+t) ----
  short8 wf[6][3];
  short8 hf[6];
  float bi[6], bh[6];
  for (int ot = 0; ot < 6; ++ot) {
    for (int ks = 0; ks < 3; ++ks) {
      short8 v;
#pragma unroll
      for (int t = 0; t < 8; ++t)
        v[t] = (short)f2bf(wih[(size_t)(16 * ot + lm) * 96 + 32 * ks + lg * 8 + t]);
      wf[ot][ks] = v;
    }
    short8 v;
#pragma unroll
    for (int t = 0; t < 8; ++t)
      v[t] = (short)f2bf(whh[(size_t)(16 * ot + lm) * 32 + lg * 8 + t]);
    hf[ot] = v;
    bi[ot] = bih[16 * ot + lm];
    bh[ot] = bhh[16 * ot + lm];
  }

  // ---- staging: global w-window [w0..w0+7] -> INS[w][row][c] (transposed) ----
  // Per row: lane loads float4 (4 w) at (c=cS, h=h0-8+row); ds_writes land
  // 2-way/bank (free): bank = c, lanes sharing c differ only in w (addr differs).
  auto stage = [&](int w0) {
#pragma unroll
    for (int half = 0; half < 2; ++half) {
      float4 buf[16];
#pragma unroll
      for (int r = 0; r < 16; ++r) {
        int row = 16 * half + r;
        int h = h0 - GR + row;
        buf[r].x = 0.f; buf[r].y = 0.f; buf[r].z = 0.f; buf[r].w = 0.f;
        if ((unsigned)h < (unsigned)Hn)
          buf[r] = *(const float4*)&states[(((size_t)b * Cn + cS) * Hn + h) * Wn + w0 + 4 * qS];
      }
#pragma unroll
      for (int r = 0; r < 16; ++r) {
        int row = 16 * half + r;
        float* dst = &INS[row * 32 + cS];
        dst[(4 * qS + 0) * 1024] = buf[r].x;
        dst[(4 * qS + 1) * 1024] = buf[r].y;
        dst[(4 * qS + 2) * 1024] = buf[r].z;
        dst[(4 * qS + 3) * 1024] = buf[r].w;
      }
    }
  };

  // ---- tile 0 inputs, then P init + output column 0 from LDS ----
  stage(0);
  for (int t = lane; t < 34 * 32; t += 64) {
    int pr = t >> 5, c = t & 31;
    int rr = pr - 1;                       // region row
    unsigned short v = 0;
    if ((unsigned)rr < 32u) v = f2bf(INS[rr * 32 + c]);  // w=0 plane (0 if OOB h)
    P[pr * PST + c] = v;                   // rows 0,33 = 0: covered by 8-step margin
  }
  for (int t = lane; t < RR * 32; t += 64) {
    int r = t >> 5, c = t & 31;
    OUTS[(r * 32 + c) * OST + 0] = INS[(r + 8) * 32 + c];  // exact f32 copy of col 0
  }

  for (int t = 0; t < NT; ++t) {
    const int w0 = WT * t;

    for (int wi = (t == 0) ? 1 : 0; wi < WT; ++wi) {
      const float* INw = &INS[wi * 1024];

      // ---- A fragments of prev column from P (read both tiles before any write) ----
      short8 af[2][3];
#pragma unroll
      for (int tl = 0; tl < 2; ++tl)
#pragma unroll
        for (int ks = 0; ks < 3; ++ks)
          af[tl][ks] = *(const short8*)&P[(16 * tl + lm + ks) * PST + lg * 8];

      // ---- cur column operands from INS (LDS only; no global traffic) ----
      short8 curA[2];
#pragma unroll
      for (int tl = 0; tl < 2; ++tl) {
        const float* ap = &INw[(16 * tl + lm) * 32 + 8 * lg];  // 8 contiguous f32
        short8 v;
#pragma unroll
        for (int u = 0; u < 8; ++u) v[u] = (short)f2bf(ap[u]);
        curA[tl] = v;
      }
      float curC[2][2][4];
#pragma unroll
      for (int tl = 0; tl < 2; ++tl)
#pragma unroll
        for (int tt = 0; tt < 2; ++tt)
#pragma unroll
          for (int i = 0; i < 4; ++i)
            curC[tl][tt][i] = INw[(16 * tl + 4 * lg + i) * 32 + 16 * tt + lm];

      // ---- per tile: MFMA -> gates -> OUT-stage write + P update ----
#pragma unroll
      for (int tl = 0; tl < 2; ++tl) {
        floatx4 I[6], Hh[6];
#pragma unroll
        for (int ot = 0; ot < 6; ++ot) {
          I[ot] = (floatx4){bi[ot], bi[ot], bi[ot], bi[ot]};
          Hh[ot] = (floatx4){bh[ot], bh[ot], bh[ot], bh[ot]};
#pragma unroll
          for (int ks = 0; ks < 3; ++ks)
            I[ot] = __builtin_amdgcn_mfma_f32_16x16x32_bf16(af[tl][ks], wf[ot][ks], I[ot], 0, 0, 0);
          Hh[ot] = __builtin_amdgcn_mfma_f32_16x16x32_bf16(curA[tl], hf[ot], Hh[ot], 0, 0, 0);
        }
#pragma unroll
        for (int tt = 0; tt < 2; ++tt) {
#pragma unroll
          for (int i = 0; i < 4; ++i) {
            float rv = sigmoidf_(I[tt][i] + Hh[tt][i]);
            float zv = sigmoidf_(I[2 + tt][i] + Hh[2 + tt][i]);
            float nv = tanhf_(I[4 + tt][i] + rv * Hh[4 + tt][i]);
            float ov = curC[tl][tt][i] + zv * (nv - curC[tl][tt][i]);
            int c = 16 * tt + lm;
            int rr = 16 * tl + lg * 4 + i;  // region row
            P[(1 + rr) * PST + c] = f2bf(ov);
            bool own = (tl == 0) ? (lg >= 2) : (lg < 2);  // region rows [8,24)
            if (own)
              OUTS[((rr - 8) * 32 + c) * OST + wi] = ov;
          }
        }
        // H-boundary chunks: force pad-adjacent ghost row to zero every column
        if (tl == 0 && j == 0 && lane < 32) P[8 * PST + lane] = 0;          // row -1
        if (tl == 1 && j == NCH - 1 && lane < 32) P[25 * PST + lane] = 0;   // row 512
      }
    }

    // ---- publish boundaries FIRST (column loop issued no vmem -> cheap release) ----
    const int par = t & 1;
    const int tag = w0 + 7;
    if (t < NT - 1) {
      const int base = (wg * 2 + par) * 256;
#pragma unroll
      for (int u0 = 0; u0 < 2; ++u0) {
        int u = lane + 64 * u0;
        int row = u >> 4, cp = (u & 15) * 2;
        unsigned int v0 = (unsigned int)P[(9 + row) * PST + cp] |
                          ((unsigned int)P[(9 + row) * PST + cp + 1] << 16);
        unsigned int v1 = (unsigned int)P[(17 + row) * PST + cp] |
                          ((unsigned int)P[(17 + row) * PST + cp + 1] << 16);
        __hip_atomic_store(&bnd[base + u], v0, __ATOMIC_RELAXED, __HIP_MEMORY_SCOPE_AGENT);
        __hip_atomic_store(&bnd[base + 128 + u], v1, __ATOMIC_RELAXED, __HIP_MEMORY_SCOPE_AGENT);
      }
      __hip_atomic_store(&flags[wg * 2 + par], tag, __ATOMIC_RELEASE, __HIP_MEMORY_SCOPE_AGENT);
    }

    // ---- flush output tile: coalesced float4 stores (w = w0..w0+7) ----
#pragma unroll
    for (int r = 0; r < RR; ++r) {
      const float* src = &OUTS[(r * 32 + cS) * OST + 4 * qS];
      float4 v;
      v.x = src[0]; v.y = src[1]; v.z = src[2]; v.w = src[3];
      *(float4*)&out[(((size_t)b * Cn + cS) * Hn + (h0 + r)) * Wn + w0 + 4 * qS] = v;
    }

    if (t < NT - 1) {
      // ---- stage next tile's inputs now; latency hides under the spin-wait ----
      stage(w0 + WT);

      if (j > 0) {  // up neighbor's bottom own rows -> ghost P rows 1..8
        const int nb = wg - 8;
        int spins = 0;
        while (__hip_atomic_load(&flags[nb * 2 + par], __ATOMIC_ACQUIRE,
                                 __HIP_MEMORY_SCOPE_AGENT) != tag) {
          __builtin_amdgcn_s_sleep(2);
          if (++spins > (1 << 20)) break;  // fail loud (wrong result), not hung
        }
#pragma unroll
        for (int u0 = 0; u0 < 2; ++u0) {
          int u = lane + 64 * u0;
          int row = u >> 4, cp = (u & 15) * 2;
          unsigned int v = __hip_atomic_load(&bnd[(nb * 2 + par) * 256 + 128 + u],
                                             __ATOMIC_RELAXED, __HIP_MEMORY_SCOPE_AGENT);
          P[(1 + row) * PST + cp] = (unsigned short)(v & 0xffffu);
          P[(1 + row) * PST + cp + 1] = (unsigned short)(v >> 16);
        }
      }
      if (j < NCH - 1) {  // down neighbor's top own rows -> ghost P rows 25..32
        const int nb = wg + 8;
        int spins = 0;
        while (__hip_atomic_load(&flags[nb * 2 + par], __ATOMIC_ACQUIRE,
                                 __HIP_MEMORY_SCOPE_AGENT) != tag) {
          __builtin_amdgcn_s_sleep(2);
          if (++spins > (1 << 20)) break;
        }
#pragma unroll
        for (int u0 = 0; u0 < 2; ++u0) {
          int u = lane + 64 * u0;
          int row = u >> 4, cp = (u & 15) * 2;
          unsigned int v = __hip_atomic_load(&bnd[(nb * 2 + par) * 256 + u],
                                             __ATOMIC_RELAXED, __HIP_MEMORY_SCOPE_AGENT);
          P[(25 + row) * PST + cp] = (unsigned short)(v & 0xffffu);
          P[(25 + row) * PST + cp + 1] = (unsigned short)(v >> 16);
        }
      }
    }
  }
}

extern "C" void kernel_launch(void* const* d_in, const int* in_sizes, int n_in,
                              void* d_out, int out_size, void* d_ws, size_t ws_size,
                              hipStream_t stream) {
  const float* states = (const float*)d_in[0];
  const float* wih = (const float*)d_in[1];
  const float* bih = (const float*)d_in[2];
  const float* whh = (const float*)d_in[3];
  const float* bhh = (const float*)d_in[4];
  float* outp = (float*)d_out;

  unsigned int* bnd = (unsigned int*)d_ws;  // NWG*2*2*128 uints = 512 KB
  int* flags = (int*)((char*)d_ws + (size_t)NWG * 2 * 256 * sizeof(unsigned int));

  // zero the epoch-tag flags each call (ws is re-poisoned by the harness)
  hipMemsetAsync(flags, 0, (size_t)NWG * 2 * sizeof(int), stream);

  sdn_scan<<<dim3(NWG), dim3(64), 0, stream>>>(states, wih, bih, whh, bhh, outp, bnd, flags);
}

// Round 3
// 1840.705 us; speedup vs baseline: 4.3021x; 1.1879x over previous
//
#include <hip/hip_runtime.h>
#include <stdint.h>
#include <stddef.h>

typedef __attribute__((ext_vector_type(8))) short short8;
typedef __attribute__((ext_vector_type(4))) float floatx4;
typedef unsigned long long u64;

#define Bn 8
#define Cn 32
#define Hn 512
#define Wn 512
#define NCH 32          // chunks per batch
#define RR 16           // own rows per chunk
#define GR 8            // ghost depth == columns per sync epoch
#define WT 8            // columns per staged tile (== GR)
#define NT (Wn/WT)      // 64 tiles
#define NWG (Bn*NCH)    // 256
#define PST 40          // P row stride (bf16 elems); 80B = 16B multiple
#define OST 9           // OUT w-stride (f32), odd pad -> conflict-light writes

__device__ __forceinline__ unsigned short f2bf(float f) {
  union { float f; unsigned int i; } v; v.f = f;
  unsigned int x = v.i;
  unsigned int r = x + 0x7fffu + ((x >> 16) & 1u);  // RNE
  return (unsigned short)(r >> 16);
}
__device__ __forceinline__ float sigmoidf_(float x) {
  return 1.0f / (1.0f + __expf(-x));
}
__device__ __forceinline__ float tanhf_(float x) {
  return 1.0f - 2.0f / (__expf(2.0f * x) + 1.0f);
}

// Ghost-zone scan + tiled LDS I/O + FENCE-FREE halo exchange.
// One wave per WG; region = 16 own + 8 ghost rows/side; halo sync every 8 cols.
// Exchange uses self-validating 64-bit words: (tile_tag << 32) | 2 x bf16, all
// RELAXED agent atomics. No acquire/release anywhere -> no buffer_inv /
// buffer_wbl2 (on gfx950 those are WHOLE-L2 invalidate/writeback; the previous
// version emitted one per spin iteration, evicting all WGs' staged data).
__global__ __launch_bounds__(64, 1) void sdn_scan(
    const float* __restrict__ states,  // (B,C,H,W) f32
    const float* __restrict__ wih,     // (96,96) f32
    const float* __restrict__ bih,     // (96)
    const float* __restrict__ whh,     // (96,32)
    const float* __restrict__ bhh,     // (96)
    float* __restrict__ out,           // (B,C,H,W) f32
    u64* __restrict__ bnd)             // [NWG][2 parity][2 dir][128] u64 = 1 MB
{
  const int lane = threadIdx.x;
  const int wg = blockIdx.x;
  const int b = wg & 7;      // batch
  const int j = wg >> 3;     // chunk within batch (neighbors wg+-8 on one XCD)
  const int h0 = j * RR;     // first OWN row
  const int lm = lane & 15;
  const int lg = lane >> 4;
  const int cS = lane >> 1;  // staging: channel
  const int qS = lane & 1;   // staging: w-quad

  __shared__ __align__(16) unsigned short P[34 * PST];   // prev column (bf16)
  __shared__ __align__(16) float INS[WT * 32 * 32];      // input tile, 32 KB
  __shared__ __align__(16) float OUTS[RR * 32 * OST];    // output tile, 18 KB

  // ---- persistent weight fragments (B-operand layout: B[k][n], n=lm, k=lg*8+t) ----
  short8 wf[6][3];
  short8 hf[6];
  float bi[6], bh[6];
  for (int ot = 0; ot < 6; ++ot) {
    for (int ks = 0; ks < 3; ++ks) {
      short8 v;
#pragma unroll
      for (int t = 0; t < 8; ++t)
        v[t] = (short)f2bf(wih[(size_t)(16 * ot + lm) * 96 + 32 * ks + lg * 8 + t]);
      wf[ot][ks] = v;
    }
    short8 v;
#pragma unroll
    for (int t = 0; t < 8; ++t)
      v[t] = (short)f2bf(whh[(size_t)(16 * ot + lm) * 32 + lg * 8 + t]);
    hf[ot] = v;
    bi[ot] = bih[16 * ot + lm];
    bh[ot] = bhh[16 * ot + lm];
  }

  // ---- staging: global w-window [w0..w0+7] -> INS[w][row][c] (transposed) ----
  auto stage = [&](int w0) {
#pragma unroll
    for (int half = 0; half < 2; ++half) {
      float4 buf[16];
#pragma unroll
      for (int r = 0; r < 16; ++r) {
        int row = 16 * half + r;
        int h = h0 - GR + row;
        buf[r].x = 0.f; buf[r].y = 0.f; buf[r].z = 0.f; buf[r].w = 0.f;
        if ((unsigned)h < (unsigned)Hn)
          buf[r] = *(const float4*)&states[(((size_t)b * Cn + cS) * Hn + h) * Wn + w0 + 4 * qS];
      }
#pragma unroll
      for (int r = 0; r < 16; ++r) {
        int row = 16 * half + r;
        float* dst = &INS[row * 32 + cS];
        dst[(4 * qS + 0) * 1024] = buf[r].x;
        dst[(4 * qS + 1) * 1024] = buf[r].y;
        dst[(4 * qS + 2) * 1024] = buf[r].z;
        dst[(4 * qS + 3) * 1024] = buf[r].w;
      }
    }
  };

  // ---- tile 0 inputs, then P init + output column 0 from LDS ----
  stage(0);
  for (int t = lane; t < 34 * 32; t += 64) {
    int pr = t >> 5, c = t & 31;
    int rr = pr - 1;                       // region row
    unsigned short v = 0;
    if ((unsigned)rr < 32u) v = f2bf(INS[rr * 32 + c]);  // w=0 plane (0 if OOB h)
    P[pr * PST + c] = v;                   // rows 0,33 = 0: covered by 8-step margin
  }
  for (int t = lane; t < RR * 32; t += 64) {
    int r = t >> 5, c = t & 31;
    OUTS[(r * 32 + c) * OST + 0] = INS[(r + 8) * 32 + c];  // exact f32 copy of col 0
  }

  for (int t = 0; t < NT; ++t) {
    const int w0 = WT * t;

    for (int wi = (t == 0) ? 1 : 0; wi < WT; ++wi) {
      const float* INw = &INS[wi * 1024];

      // ---- A fragments of prev column from P (read both tiles before any write) ----
      short8 af[2][3];
#pragma unroll
      for (int tl = 0; tl < 2; ++tl)
#pragma unroll
        for (int ks = 0; ks < 3; ++ks)
          af[tl][ks] = *(const short8*)&P[(16 * tl + lm + ks) * PST + lg * 8];

      // ---- cur column operands from INS (LDS only; no global traffic) ----
      short8 curA[2];
#pragma unroll
      for (int tl = 0; tl < 2; ++tl) {
        const float* ap = &INw[(16 * tl + lm) * 32 + 8 * lg];  // 8 contiguous f32
        short8 v;
#pragma unroll
        for (int u = 0; u < 8; ++u) v[u] = (short)f2bf(ap[u]);
        curA[tl] = v;
      }
      float curC[2][2][4];
#pragma unroll
      for (int tl = 0; tl < 2; ++tl)
#pragma unroll
        for (int tt = 0; tt < 2; ++tt)
#pragma unroll
          for (int i = 0; i < 4; ++i)
            curC[tl][tt][i] = INw[(16 * tl + 4 * lg + i) * 32 + 16 * tt + lm];

      // ---- per tile: MFMA -> gates -> OUT-stage write + P update ----
#pragma unroll
      for (int tl = 0; tl < 2; ++tl) {
        floatx4 I[6], Hh[6];
#pragma unroll
        for (int ot = 0; ot < 6; ++ot) {
          I[ot] = (floatx4){bi[ot], bi[ot], bi[ot], bi[ot]};
          Hh[ot] = (floatx4){bh[ot], bh[ot], bh[ot], bh[ot]};
#pragma unroll
          for (int ks = 0; ks < 3; ++ks)
            I[ot] = __builtin_amdgcn_mfma_f32_16x16x32_bf16(af[tl][ks], wf[ot][ks], I[ot], 0, 0, 0);
          Hh[ot] = __builtin_amdgcn_mfma_f32_16x16x32_bf16(curA[tl], hf[ot], Hh[ot], 0, 0, 0);
        }
#pragma unroll
        for (int tt = 0; tt < 2; ++tt) {
#pragma unroll
          for (int i = 0; i < 4; ++i) {
            float rv = sigmoidf_(I[tt][i] + Hh[tt][i]);
            float zv = sigmoidf_(I[2 + tt][i] + Hh[2 + tt][i]);
            float nv = tanhf_(I[4 + tt][i] + rv * Hh[4 + tt][i]);
            float ov = curC[tl][tt][i] + zv * (nv - curC[tl][tt][i]);
            int c = 16 * tt + lm;
            int rr = 16 * tl + lg * 4 + i;  // region row
            P[(1 + rr) * PST + c] = f2bf(ov);
            bool own = (tl == 0) ? (lg >= 2) : (lg < 2);  // region rows [8,24)
            if (own)
              OUTS[((rr - 8) * 32 + c) * OST + wi] = ov;
          }
        }
        // H-boundary chunks: force pad-adjacent ghost row to zero every column
        if (tl == 0 && j == 0 && lane < 32) P[8 * PST + lane] = 0;          // row -1
        if (tl == 1 && j == NCH - 1 && lane < 32) P[25 * PST + lane] = 0;   // row 512
      }
    }

    const int par = t & 1;
    const unsigned int tag = (unsigned int)(w0 + 7);  // >= 7, never 0

    // ---- publish boundaries: self-validating u64 words, RELAXED (no fence) ----
    if (t < NT - 1) {
      u64* dst = &bnd[(size_t)(wg * 2 + par) * 256];
#pragma unroll
      for (int u0 = 0; u0 < 2; ++u0) {
        int u = lane + 64 * u0;
        int row = u >> 4, cp = (u & 15) * 2;
        u64 v0 = (u64)((unsigned int)P[(9 + row) * PST + cp] |
                       ((unsigned int)P[(9 + row) * PST + cp + 1] << 16)) | ((u64)tag << 32);
        u64 v1 = (u64)((unsigned int)P[(17 + row) * PST + cp] |
                       ((unsigned int)P[(17 + row) * PST + cp + 1] << 16)) | ((u64)tag << 32);
        __hip_atomic_store(&dst[u], v0, __ATOMIC_RELAXED, __HIP_MEMORY_SCOPE_AGENT);
        __hip_atomic_store(&dst[128 + u], v1, __ATOMIC_RELAXED, __HIP_MEMORY_SCOPE_AGENT);
      }
    }

    // ---- flush output tile: coalesced float4 stores (w = w0..w0+7) ----
#pragma unroll
    for (int r = 0; r < RR; ++r) {
      const float* src = &OUTS[(r * 32 + cS) * OST + 4 * qS];
      float4 v;
      v.x = src[0]; v.y = src[1]; v.z = src[2]; v.w = src[3];
      *(float4*)&out[(((size_t)b * Cn + cS) * Hn + (h0 + r)) * Wn + w0 + 4 * qS] = v;
    }

    if (t < NT - 1) {
      // ---- stage next tile's inputs (L2 stays valid now -> mostly L2 hits) ----
      stage(w0 + WT);

      // ---- consume neighbor boundaries: per-word tag spin, RELAXED only ----
      if (j > 0) {  // up neighbor's bottom own rows (dir1) -> ghost P rows 1..8
        const u64* src = &bnd[(size_t)((wg - 8) * 2 + par) * 256 + 128];
#pragma unroll
        for (int u0 = 0; u0 < 2; ++u0) {
          int u = lane + 64 * u0;
          u64 v; int spins = 0;
          while (true) {
            v = __hip_atomic_load(&src[u], __ATOMIC_RELAXED, __HIP_MEMORY_SCOPE_AGENT);
            if ((unsigned int)(v >> 32) == tag) break;
            __builtin_amdgcn_s_sleep(2);
            if (++spins > (1 << 20)) break;  // fail loud (wrong result), not hung
          }
          int row = u >> 4, cp = (u & 15) * 2;
          P[(1 + row) * PST + cp] = (unsigned short)(v & 0xffffu);
          P[(1 + row) * PST + cp + 1] = (unsigned short)((v >> 16) & 0xffffu);
        }
      }
      if (j < NCH - 1) {  // down neighbor's top own rows (dir0) -> ghost P rows 25..32
        const u64* src = &bnd[(size_t)((wg + 8) * 2 + par) * 256];
#pragma unroll
        for (int u0 = 0; u0 < 2; ++u0) {
          int u = lane + 64 * u0;
          u64 v; int spins = 0;
          while (true) {
            v = __hip_atomic_load(&src[u], __ATOMIC_RELAXED, __HIP_MEMORY_SCOPE_AGENT);
            if ((unsigned int)(v >> 32) == tag) break;
            __builtin_amdgcn_s_sleep(2);
            if (++spins > (1 << 20)) break;
          }
          int row = u >> 4, cp = (u & 15) * 2;
          P[(25 + row) * PST + cp] = (unsigned short)(v & 0xffffu);
          P[(25 + row) * PST + cp + 1] = (unsigned short)((v >> 16) & 0xffffu);
        }
      }
    }
  }
}

extern "C" void kernel_launch(void* const* d_in, const int* in_sizes, int n_in,
                              void* d_out, int out_size, void* d_ws, size_t ws_size,
                              hipStream_t stream) {
  const float* states = (const float*)d_in[0];
  const float* wih = (const float*)d_in[1];
  const float* bih = (const float*)d_in[2];
  const float* whh = (const float*)d_in[3];
  const float* bhh = (const float*)d_in[4];
  float* outp = (float*)d_out;

  u64* bnd = (u64*)d_ws;  // NWG*2*2*128 u64 = 1 MB

  // zero tags each call (ws is re-poisoned by the harness; tag 0 is never valid)
  hipMemsetAsync(bnd, 0, (size_t)NWG * 2 * 256 * sizeof(u64), stream);

  sdn_scan<<<dim3(NWG), dim3(64), 0, stream>>>(states, wih, bih, whh, bhh, outp, bnd);
}

// Round 4
// 968.013 us; speedup vs baseline: 8.1805x; 1.9015x over previous
//
#include <hip/hip_runtime.h>
#include <stdint.h>
#include <stddef.h>

typedef __attribute__((ext_vector_type(8))) short short8;
typedef __attribute__((ext_vector_type(4))) float floatx4;
typedef unsigned long long u64;

#define Bn 8
#define Cn 32
#define Hn 512
#define Wn 512
#define NCH 32          // chunks per batch
#define RR 16           // own rows per chunk
#define GR 8            // ghost depth == columns per sync epoch
#define WT 8            // columns per staged tile (== GR)
#define NT (Wn/WT)      // 64 tiles
#define NWG (Bn*NCH)    // 256
#define PST 40          // P row stride (bf16 elems); 80B = 16B multiple
#define OST 9           // OUT w-stride (f32), odd pad -> conflict-light writes

__device__ __forceinline__ unsigned short f2bf(float f) {
  union { float f; unsigned int i; } v; v.f = f;
  unsigned int x = v.i;
  unsigned int r = x + 0x7fffu + ((x >> 16) & 1u);  // RNE
  return (unsigned short)(r >> 16);
}
__device__ __forceinline__ float sigmoidf_(float x) {
  return 1.0f / (1.0f + __expf(-x));
}
__device__ __forceinline__ float tanhf_(float x) {
  return 1.0f - 2.0f / (__expf(2.0f * x) + 1.0f);
}

// Ghost-zone scan, tiled LDS I/O, fence-free tagged exchange -- now with a
// 4-WAVE workgroup so the CU's 4 SIMDs work one column cooperatively:
//   wave (tl,tt) owns output quadrant rows [16tl,16tl+16) x ch [16tt,16tt+16)
//   (3 I-MFMAs x 3ks + 3 Hh-MFMAs + gates for 4 elems/lane)
// Two s_barriers per column (read-phase / write-phase). Spin-wait is one
// tagged u64 per THREAD (256 concurrent polls, was 4 sequential wave loops).
__global__ __launch_bounds__(256, 1) void sdn_scan(
    const float* __restrict__ states,  // (B,C,H,W) f32
    const float* __restrict__ wih,     // (96,96) f32
    const float* __restrict__ bih,     // (96)
    const float* __restrict__ whh,     // (96,32)
    const float* __restrict__ bhh,     // (96)
    float* __restrict__ out,           // (B,C,H,W) f32
    u64* __restrict__ bnd)             // [NWG][2 parity][2 dir][128] u64 = 1 MB
{
  const int tid = threadIdx.x;
  const int lane = tid & 63;
  const int wid = tid >> 6;
  const int tl = wid >> 1;   // row-tile this wave owns
  const int tt = wid & 1;    // channel-half this wave owns
  const int wg = blockIdx.x;
  const int b = wg & 7;      // batch
  const int j = wg >> 3;     // chunk within batch (neighbors wg+-8 on one XCD)
  const int h0 = j * RR;     // first OWN row
  const int lm = lane & 15;
  const int lg = lane >> 4;
  const int cS = lane >> 1;  // staging: channel
  const int qS = lane & 1;   // staging: w-quad

  __shared__ __align__(16) unsigned short P[34 * PST];   // prev column (bf16)
  __shared__ __align__(16) float INS[WT * 32 * 32];      // input tile, 32 KB
  __shared__ __align__(16) float OUTS[RR * 32 * OST];    // output tile, 18 KB

  // ---- this wave's weight fragments: ot = 2*q + tt, q=0..2 (r,z,n gates) ----
  short8 wf[3][3];
  short8 hf[3];
  float bi[3], bh[3];
  for (int q = 0; q < 3; ++q) {
    const int ot = 2 * q + tt;
    for (int ks = 0; ks < 3; ++ks) {
      short8 v;
#pragma unroll
      for (int t = 0; t < 8; ++t)
        v[t] = (short)f2bf(wih[(size_t)(16 * ot + lm) * 96 + 32 * ks + lg * 8 + t]);
      wf[q][ks] = v;
    }
    short8 v;
#pragma unroll
    for (int t = 0; t < 8; ++t)
      v[t] = (short)f2bf(whh[(size_t)(16 * ot + lm) * 32 + lg * 8 + t]);
    hf[q] = v;
    bi[q] = bih[16 * ot + lm];
    bh[q] = bhh[16 * ot + lm];
  }

  // ---- staging: global w-window [w0..w0+7] -> INS[w][row][c]; wave owns 8 rows ----
  auto stage = [&](int w0) {
    float4 buf[8];
#pragma unroll
    for (int r = 0; r < 8; ++r) {
      int row = 8 * wid + r;
      int h = h0 - GR + row;
      buf[r].x = 0.f; buf[r].y = 0.f; buf[r].z = 0.f; buf[r].w = 0.f;
      if ((unsigned)h < (unsigned)Hn)
        buf[r] = *(const float4*)&states[(((size_t)b * Cn + cS) * Hn + h) * Wn + w0 + 4 * qS];
    }
#pragma unroll
    for (int r = 0; r < 8; ++r) {
      int row = 8 * wid + r;
      float* dst = &INS[row * 32 + cS];
      dst[(4 * qS + 0) * 1024] = buf[r].x;
      dst[(4 * qS + 1) * 1024] = buf[r].y;
      dst[(4 * qS + 2) * 1024] = buf[r].z;
      dst[(4 * qS + 3) * 1024] = buf[r].w;
    }
  };

  // ---- tile 0 inputs, then P init + output column 0 from LDS ----
  stage(0);
  __syncthreads();
  for (int t = tid; t < 34 * 32; t += 256) {
    int pr = t >> 5, c = t & 31;
    int rr = pr - 1;                       // region row
    unsigned short v = 0;
    if ((unsigned)rr < 32u) v = f2bf(INS[rr * 32 + c]);  // w=0 plane (0 if OOB h)
    P[pr * PST + c] = v;                   // rows 0,33 = 0: covered by 8-step margin
  }
  for (int t = tid; t < RR * 32; t += 256) {
    int r = t >> 5, c = t & 31;
    OUTS[(r * 32 + c) * OST + 0] = INS[(r + 8) * 32 + c];  // exact f32 copy of col 0
  }
  __syncthreads();

  for (int t = 0; t < NT; ++t) {
    const int w0 = WT * t;

    for (int wi = (t == 0) ? 1 : 0; wi < WT; ++wi) {
      const float* INw = &INS[wi * 1024];

      // ---- READ PHASE: this wave's A fragments + cur operands ----
      short8 af[3];
#pragma unroll
      for (int ks = 0; ks < 3; ++ks)
        af[ks] = *(const short8*)&P[(16 * tl + lm + ks) * PST + lg * 8];

      short8 curA;
      {
        const float* ap = &INw[(16 * tl + lm) * 32 + 8 * lg];  // 8 contiguous f32
#pragma unroll
        for (int u = 0; u < 8; ++u) curA[u] = (short)f2bf(ap[u]);
      }
      float curC[4];
#pragma unroll
      for (int i = 0; i < 4; ++i)
        curC[i] = INw[(16 * tl + 4 * lg + i) * 32 + 16 * tt + lm];

      __syncthreads();  // all P reads done before any P write

      // ---- WRITE PHASE: MFMA -> gates -> P update + OUT-stage write ----
      floatx4 I[3], Hh[3];
#pragma unroll
      for (int q = 0; q < 3; ++q) {
        I[q] = (floatx4){bi[q], bi[q], bi[q], bi[q]};
        Hh[q] = (floatx4){bh[q], bh[q], bh[q], bh[q]};
#pragma unroll
        for (int ks = 0; ks < 3; ++ks)
          I[q] = __builtin_amdgcn_mfma_f32_16x16x32_bf16(af[ks], wf[q][ks], I[q], 0, 0, 0);
        Hh[q] = __builtin_amdgcn_mfma_f32_16x16x32_bf16(curA, hf[q], Hh[q], 0, 0, 0);
      }
#pragma unroll
      for (int i = 0; i < 4; ++i) {
        float rv = sigmoidf_(I[0][i] + Hh[0][i]);
        float zv = sigmoidf_(I[1][i] + Hh[1][i]);
        float nv = tanhf_(I[2][i] + rv * Hh[2][i]);
        float ov = curC[i] + zv * (nv - curC[i]);
        int c = 16 * tt + lm;
        int rr = 16 * tl + 4 * lg + i;  // region row
        // H-edge chunks: pad-adjacent ghost row is forced to 0 (reference zero-pad)
        unsigned short pv = f2bf(ov);
        if ((j == 0 && rr == 7) || (j == NCH - 1 && rr == 24)) pv = 0;
        P[(1 + rr) * PST + c] = pv;
        bool own = (tl == 0) ? (lg >= 2) : (lg < 2);  // region rows [8,24)
        if (own)
          OUTS[((rr - 8) * 32 + c) * OST + wi] = ov;
      }

      __syncthreads();  // writes visible before next column's reads
    }

    const int par = t & 1;
    const unsigned int tag = (unsigned int)(w0 + 7);  // >= 7, never 0

    // ---- publish boundaries: one tagged u64 per thread, RELAXED (no fence) ----
    if (t < NT - 1) {
      const int dir = tid >> 7;          // 0: my top own rows, 1: my bottom own rows
      const int idx = tid & 127;
      const int row = idx >> 4, cp = (idx & 15) * 2;
      const int prow = (dir ? 17 : 9) + row;
      u64 v = (u64)((unsigned int)P[prow * PST + cp] |
                    ((unsigned int)P[prow * PST + cp + 1] << 16)) | ((u64)tag << 32);
      __hip_atomic_store(&bnd[(size_t)(wg * 2 + par) * 256 + tid], v,
                         __ATOMIC_RELAXED, __HIP_MEMORY_SCOPE_AGENT);
    }

    // ---- flush output tile: coalesced float4 stores; wave owns 4 rows ----
#pragma unroll
    for (int r4 = 0; r4 < 4; ++r4) {
      int r = 4 * wid + r4;
      const float* src = &OUTS[(r * 32 + cS) * OST + 4 * qS];
      float4 v;
      v.x = src[0]; v.y = src[1]; v.z = src[2]; v.w = src[3];
      *(float4*)&out[(((size_t)b * Cn + cS) * Hn + (h0 + r)) * Wn + w0 + 4 * qS] = v;
    }

    if (t < NT - 1) {
      // ---- stage next tile's inputs; HBM latency overlaps the spin below ----
      stage(w0 + WT);

      // ---- consume neighbor boundaries: one tagged word per thread ----
      if (tid < 128) {
        if (j > 0) {  // up neighbor's bottom own rows (dir1) -> ghost P rows 1..8
          const u64* src = &bnd[(size_t)((wg - 8) * 2 + par) * 256 + 128 + tid];
          u64 v; int spins = 0;
          while (true) {
            v = __hip_atomic_load(src, __ATOMIC_RELAXED, __HIP_MEMORY_SCOPE_AGENT);
            if ((unsigned int)(v >> 32) == tag) break;
            __builtin_amdgcn_s_sleep(2);
            if (++spins > (1 << 20)) break;  // fail loud (wrong result), not hung
          }
          int row = tid >> 4, cp = (tid & 15) * 2;
          P[(1 + row) * PST + cp] = (unsigned short)(v & 0xffffu);
          P[(1 + row) * PST + cp + 1] = (unsigned short)((v >> 16) & 0xffffu);
        }
      } else {
        if (j < NCH - 1) {  // down neighbor's top own rows (dir0) -> ghost P rows 25..32
          const int idx = tid - 128;
          const u64* src = &bnd[(size_t)((wg + 8) * 2 + par) * 256 + idx];
          u64 v; int spins = 0;
          while (true) {
            v = __hip_atomic_load(src, __ATOMIC_RELAXED, __HIP_MEMORY_SCOPE_AGENT);
            if ((unsigned int)(v >> 32) == tag) break;
            __builtin_amdgcn_s_sleep(2);
            if (++spins > (1 << 20)) break;
          }
          int row = idx >> 4, cp = (idx & 15) * 2;
          P[(25 + row) * PST + cp] = (unsigned short)(v & 0xffffu);
          P[(25 + row) * PST + cp + 1] = (unsigned short)((v >> 16) & 0xffffu);
        }
      }

      __syncthreads();  // ghost rows + staged INS visible before next tile's reads
    }
  }
}

extern "C" void kernel_launch(void* const* d_in, const int* in_sizes, int n_in,
                              void* d_out, int out_size, void* d_ws, size_t ws_size,
                              hipStream_t stream) {
  const float* states = (const float*)d_in[0];
  const float* wih = (const float*)d_in[1];
  const float* bih = (const float*)d_in[2];
  const float* whh = (const float*)d_in[3];
  const float* bhh = (const float*)d_in[4];
  float* outp = (float*)d_out;

  u64* bnd = (u64*)d_ws;  // NWG*2*2*128 u64 = 1 MB

  // zero tags each call (ws is re-poisoned by the harness; tag 0 is never valid)
  hipMemsetAsync(bnd, 0, (size_t)NWG * 2 * 256 * sizeof(u64), stream);

  sdn_scan<<<dim3(NWG), dim3(256), 0, stream>>>(states, wih, bih, whh, bhh, outp, bnd);
}

// Round 5
// 813.642 us; speedup vs baseline: 9.7326x; 1.1897x over previous
//
#include <hip/hip_runtime.h>
#include <stdint.h>
#include <stddef.h>

typedef __attribute__((ext_vector_type(8))) short short8;
typedef __attribute__((ext_vector_type(4))) float floatx4;
typedef unsigned long long u64;

#define Bn 8
#define Cn 32
#define Hn 512
#define Wn 512
#define NCH 32          // chunks per batch
#define RR 16           // own rows per chunk
#define GR 8            // ghost depth == columns per sync epoch
#define WT 8            // columns per staged tile (== GR)
#define NT (Wn/WT)      // 64 tiles
#define NWG (Bn*NCH)    // 256
#define PST 40          // P row stride (bf16); 80B = 16B multiple
#define IST 40          // INB row stride (bf16); breaks power-of-2 bank aliasing
#define IPL (32*IST)    // INB plane stride (shorts)

__device__ __forceinline__ unsigned short f2bf(float f) {
  union { float f; unsigned int i; } v; v.f = f;
  unsigned int x = v.i;
  unsigned int r = x + 0x7fffu + ((x >> 16) & 1u);  // RNE
  return (unsigned short)(r >> 16);
}
__device__ __forceinline__ float sigmoidf_(float x) {
  return 1.0f / (1.0f + __expf(-x));
}
__device__ __forceinline__ float tanhf_(float x) {
  return 1.0f - 2.0f / (__expf(2.0f * x) + 1.0f);
}

// Ghost-zone scan, 4-wave cooperative columns, fence-free tagged exchange.
// Round-5 structure: ONE barrier per column (double-buffered P), curA/curC
// prefetched a column ahead (bf16 input tile INB staged once per tile),
// af LDS latency hidden under the independent Hh MFMAs, outputs kept in
// registers and flushed straight to global, next-tile global loads issued
// at tile TOP (T14 split) so HBM latency overlaps 8 columns of compute.
__global__ __launch_bounds__(256, 1) void sdn_scan(
    const float* __restrict__ states,  // (B,C,H,W) f32
    const float* __restrict__ wih,     // (96,96) f32
    const float* __restrict__ bih,     // (96)
    const float* __restrict__ whh,     // (96,32)
    const float* __restrict__ bhh,     // (96)
    float* __restrict__ out,           // (B,C,H,W) f32
    u64* __restrict__ bnd)             // [NWG][2 parity][2 dir][128] u64 = 1 MB
{
  const int tid = threadIdx.x;
  const int lane = tid & 63;
  const int wid = tid >> 6;
  const int tl = wid >> 1;   // row-tile this wave owns
  const int tt = wid & 1;    // channel-half this wave owns
  const int wg = blockIdx.x;
  const int b = wg & 7;      // batch
  const int j = wg >> 3;     // chunk within batch (neighbors wg+-8 on one XCD)
  const int h0 = j * RR;     // first OWN row
  const int lm = lane & 15;
  const int lg = lane >> 4;
  const int cS = lane >> 1;  // staging: channel
  const int qS = lane & 1;   // staging: w-quad

  __shared__ __align__(16) unsigned short Pb[2][34 * PST];  // prev column, dbuf
  __shared__ __align__(16) float INS[WT * 32 * 32];         // input tile f32, 32 KB
  __shared__ __align__(16) unsigned short INB[WT * IPL];    // input tile bf16, 20 KB

  // ---- this wave's weight fragments: ot = 2*q + tt, q=0..2 (r,z,n gates) ----
  short8 wf[3][3];
  short8 hf[3];
  float bi[3], bh[3];
  for (int q = 0; q < 3; ++q) {
    const int ot = 2 * q + tt;
    for (int ks = 0; ks < 3; ++ks) {
      short8 v;
#pragma unroll
      for (int t = 0; t < 8; ++t)
        v[t] = (short)f2bf(wih[(size_t)(16 * ot + lm) * 96 + 32 * ks + lg * 8 + t]);
      wf[q][ks] = v;
    }
    short8 v;
#pragma unroll
    for (int t = 0; t < 8; ++t)
      v[t] = (short)f2bf(whh[(size_t)(16 * ot + lm) * 32 + lg * 8 + t]);
    hf[q] = v;
    bi[q] = bih[16 * ot + lm];
    bh[q] = bhh[16 * ot + lm];
  }

  // ---- prologue: stage tile 0 (immediate), both f32 and bf16 copies ----
  {
    float4 buf[8];
#pragma unroll
    for (int r = 0; r < 8; ++r) {
      int row = 8 * wid + r;
      int h = h0 - GR + row;
      buf[r].x = 0.f; buf[r].y = 0.f; buf[r].z = 0.f; buf[r].w = 0.f;
      if ((unsigned)h < (unsigned)Hn)
        buf[r] = *(const float4*)&states[(((size_t)b * Cn + cS) * Hn + h) * Wn + 4 * qS];
    }
#pragma unroll
    for (int r = 0; r < 8; ++r) {
      int row = 8 * wid + r;
      float* dst = &INS[row * 32 + cS];
      unsigned short* bdst = &INB[row * IST + cS];
      dst[(4 * qS + 0) * 1024] = buf[r].x;  bdst[(4 * qS + 0) * IPL] = f2bf(buf[r].x);
      dst[(4 * qS + 1) * 1024] = buf[r].y;  bdst[(4 * qS + 1) * IPL] = f2bf(buf[r].y);
      dst[(4 * qS + 2) * 1024] = buf[r].z;  bdst[(4 * qS + 2) * IPL] = f2bf(buf[r].z);
      dst[(4 * qS + 3) * 1024] = buf[r].w;  bdst[(4 * qS + 3) * IPL] = f2bf(buf[r].w);
    }
  }
  __syncthreads();

  // ---- P init: column 0 into Pb[0]; zero the never-written pad rows of Pb[1] ----
  for (int t = tid; t < 34 * 32; t += 256) {
    int pr = t >> 5, c = t & 31;
    int rr = pr - 1;                       // region row
    unsigned short v = 0;
    if ((unsigned)rr < 32u) v = f2bf(INS[rr * 32 + c]);  // w=0 plane
    Pb[0][pr * PST + c] = v;               // rows 0,33 = 0 (8-step ghost margin)
  }
  if (tid < 64) {
    int pr = (tid >= 32) ? 33 : 0, c = tid & 31;
    Pb[1][pr * PST + c] = 0;
  }
  __syncthreads();

  // ---- own outputs live in registers; col 0 = exact input copy ----
  float oreg[4][8];
  {
    const int c = 16 * tt + lm;
#pragma unroll
    for (int i = 0; i < 4; ++i)
      oreg[i][0] = INS[(16 * tl + 4 * lg + i) * 32 + c];
  }

  int cur = 0;  // Pb[cur] holds the latest completed column

  for (int t = 0; t < NT; ++t) {
    const int w0 = WT * t;

    // ---- tile-top: ISSUE next tile's global loads (held in regs all tile) ----
    float4 sbuf[8];
    if (t < NT - 1) {
#pragma unroll
      for (int r = 0; r < 8; ++r) {
        int row = 8 * wid + r;
        int h = h0 - GR + row;
        sbuf[r].x = 0.f; sbuf[r].y = 0.f; sbuf[r].z = 0.f; sbuf[r].w = 0.f;
        if ((unsigned)h < (unsigned)Hn)
          sbuf[r] = *(const float4*)&states[(((size_t)b * Cn + cS) * Hn + h) * Wn + (w0 + WT) + 4 * qS];
      }
    }

    // ---- prefetch first computed column's operands ----
    const int wf0 = (t == 0) ? 1 : 0;
    short8 curA = *(const short8*)&INB[wf0 * IPL + (16 * tl + lm) * IST + 8 * lg];
    float curC[4];
#pragma unroll
    for (int i = 0; i < 4; ++i)
      curC[i] = INS[wf0 * 1024 + (16 * tl + 4 * lg + i) * 32 + 16 * tt + lm];

#pragma unroll
    for (int wi = 0; wi < WT; ++wi) {
      if (t == 0 && wi == 0) continue;   // col 0 handled above (uniform branch)
      const unsigned short* Pc = Pb[cur];
      unsigned short* Pn = Pb[cur ^ 1];

      // issue af reads; the independent Hh MFMAs below cover their latency
      short8 af[3];
#pragma unroll
      for (int ks = 0; ks < 3; ++ks)
        af[ks] = *(const short8*)&Pc[(16 * tl + lm + ks) * PST + 8 * lg];

      floatx4 I[3], Hh[3];
#pragma unroll
      for (int q = 0; q < 3; ++q) {
        Hh[q] = (floatx4){bh[q], bh[q], bh[q], bh[q]};
        Hh[q] = __builtin_amdgcn_mfma_f32_16x16x32_bf16(curA, hf[q], Hh[q], 0, 0, 0);
      }
#pragma unroll
      for (int q = 0; q < 3; ++q) {
        I[q] = (floatx4){bi[q], bi[q], bi[q], bi[q]};
#pragma unroll
        for (int ks = 0; ks < 3; ++ks)
          I[q] = __builtin_amdgcn_mfma_f32_16x16x32_bf16(af[ks], wf[q][ks], I[q], 0, 0, 0);
      }

      // prefetch NEXT column's operands (read-only LDS; hides under gates)
      short8 nA = curA;
      float nC[4] = {curC[0], curC[1], curC[2], curC[3]};
      if (wi < WT - 1) {
        nA = *(const short8*)&INB[(wi + 1) * IPL + (16 * tl + lm) * IST + 8 * lg];
#pragma unroll
        for (int i = 0; i < 4; ++i)
          nC[i] = INS[(wi + 1) * 1024 + (16 * tl + 4 * lg + i) * 32 + 16 * tt + lm];
      }

      const int c = 16 * tt + lm;
#pragma unroll
      for (int i = 0; i < 4; ++i) {
        float rv = sigmoidf_(I[0][i] + Hh[0][i]);
        float zv = sigmoidf_(I[1][i] + Hh[1][i]);
        float nv = tanhf_(I[2][i] + rv * Hh[2][i]);
        float ov = curC[i] + zv * (nv - curC[i]);
        int rr = 16 * tl + 4 * lg + i;  // region row
        unsigned short pv = f2bf(ov);
        // H-edge chunks: pad-adjacent ghost row forced to 0 (reference zero-pad)
        if ((j == 0 && rr == 7) || (j == NCH - 1 && rr == 24)) pv = 0;
        Pn[(1 + rr) * PST + c] = pv;
        oreg[i][wi] = ov;               // static indices -> stays in VGPRs
      }

      __syncthreads();                   // single barrier per column
      cur ^= 1;
      curA = nA;
#pragma unroll
      for (int i = 0; i < 4; ++i) curC[i] = nC[i];
    }
    // invariant: last computed column index is odd -> cur == 1 here

    const int par = t & 1;
    const unsigned int tag = (unsigned int)(w0 + 7);  // >= 7, never 0

    // 1) publish own boundary rows from Pb[1] ASAP (unblocks neighbors)
    if (t < NT - 1) {
      const int dir = tid >> 7;          // 0: top own rows, 1: bottom own rows
      const int idx = tid & 127;
      const int row = idx >> 4, cp = (idx & 15) * 2;
      const int prow = (dir ? 17 : 9) + row;
      u64 v = (u64)((unsigned int)Pb[1][prow * PST + cp] |
                    ((unsigned int)Pb[1][prow * PST + cp + 1] << 16)) | ((u64)tag << 32);
      __hip_atomic_store(&bnd[(size_t)(wg * 2 + par) * 256 + tid], v,
                         __ATOMIC_RELAXED, __HIP_MEMORY_SCOPE_AGENT);
    }

    // 2) stage-write next tile's INS/INB (sbuf loads landed long ago)
    if (t < NT - 1) {
#pragma unroll
      for (int r = 0; r < 8; ++r) {
        int row = 8 * wid + r;
        float* dst = &INS[row * 32 + cS];
        unsigned short* bdst = &INB[row * IST + cS];
        dst[(4 * qS + 0) * 1024] = sbuf[r].x;  bdst[(4 * qS + 0) * IPL] = f2bf(sbuf[r].x);
        dst[(4 * qS + 1) * 1024] = sbuf[r].y;  bdst[(4 * qS + 1) * IPL] = f2bf(sbuf[r].y);
        dst[(4 * qS + 2) * 1024] = sbuf[r].z;  bdst[(4 * qS + 2) * IPL] = f2bf(sbuf[r].z);
        dst[(4 * qS + 3) * 1024] = sbuf[r].w;  bdst[(4 * qS + 3) * IPL] = f2bf(sbuf[r].w);
      }
    }

    // 3) flush own outputs straight from registers (two float4 per row)
    {
      const bool own = (tl == 0) ? (lg >= 2) : (lg < 2);  // region rows [8,24)
      if (own) {
        const int c = 16 * tt + lm;
#pragma unroll
        for (int i = 0; i < 4; ++i) {
          int h = h0 + (16 * tl + 4 * lg + i) - 8;
          float4 lo; lo.x = oreg[i][0]; lo.y = oreg[i][1]; lo.z = oreg[i][2]; lo.w = oreg[i][3];
          float4 hi; hi.x = oreg[i][4]; hi.y = oreg[i][5]; hi.z = oreg[i][6]; hi.w = oreg[i][7];
          float* op = &out[(((size_t)b * Cn + c) * Hn + h) * Wn + w0];
          *(float4*)op = lo;
          *(float4*)(op + 4) = hi;
        }
      }
    }

    // 4) consume neighbor boundaries into Pb[1] ghost rows, then tile barrier
    if (t < NT - 1) {
      if (tid < 128) {
        if (j > 0) {  // up neighbor's bottom own rows (dir1) -> ghost rows 1..8
          const u64* src = &bnd[(size_t)((wg - 8) * 2 + par) * 256 + 128 + tid];
          u64 v; int spins = 0;
          while (true) {
            v = __hip_atomic_load(src, __ATOMIC_RELAXED, __HIP_MEMORY_SCOPE_AGENT);
            if ((unsigned int)(v >> 32) == tag) break;
            __builtin_amdgcn_s_sleep(2);
            if (++spins > (1 << 20)) break;  // fail loud, not hung
          }
          int row = tid >> 4, cp = (tid & 15) * 2;
          Pb[1][(1 + row) * PST + cp] = (unsigned short)(v & 0xffffu);
          Pb[1][(1 + row) * PST + cp + 1] = (unsigned short)((v >> 16) & 0xffffu);
        }
      } else {
        if (j < NCH - 1) {  // down neighbor's top own rows (dir0) -> ghost 25..32
          const int idx = tid - 128;
          const u64* src = &bnd[(size_t)((wg + 8) * 2 + par) * 256 + idx];
          u64 v; int spins = 0;
          while (true) {
            v = __hip_atomic_load(src, __ATOMIC_RELAXED, __HIP_MEMORY_SCOPE_AGENT);
            if ((unsigned int)(v >> 32) == tag) break;
            __builtin_amdgcn_s_sleep(2);
            if (++spins > (1 << 20)) break;
          }
          int row = idx >> 4, cp = (idx & 15) * 2;
          Pb[1][(25 + row) * PST + cp] = (unsigned short)(v & 0xffffu);
          Pb[1][(25 + row) * PST + cp + 1] = (unsigned short)((v >> 16) & 0xffffu);
        }
      }
      __syncthreads();  // ghost rows + staged INS/INB visible to next tile
    }
  }
}

extern "C" void kernel_launch(void* const* d_in, const int* in_sizes, int n_in,
                              void* d_out, int out_size, void* d_ws, size_t ws_size,
                              hipStream_t stream) {
  const float* states = (const float*)d_in[0];
  const float* wih = (const float*)d_in[1];
  const float* bih = (const float*)d_in[2];
  const float* whh = (const float*)d_in[3];
  const float* bhh = (const float*)d_in[4];
  float* outp = (float*)d_out;

  u64* bnd = (u64*)d_ws;  // NWG*2*2*128 u64 = 1 MB

  // zero tags each call (ws is re-poisoned by the harness; tag 0 is never valid)
  hipMemsetAsync(bnd, 0, (size_t)NWG * 2 * 256 * sizeof(u64), stream);

  sdn_scan<<<dim3(NWG), dim3(256), 0, stream>>>(states, wih, bih, whh, bhh, outp, bnd);
}